// Round 12
// baseline (2075.417 us; speedup 1.0000x reference)
//
#include <hip/hip_runtime.h>
#include <hip/hip_bf16.h>
#include <cstdint>
#include <cstddef>

// ---- model dims ----
constexpr int LNUM = 12;
constexpr int BB   = 2;
constexpr int SS   = 1024;
constexpr int CC   = 768;
constexpr int HH   = 12;
constexpr int DD   = 64;      // C/H
constexpr int FFD  = 3072;    // 4C
constexpr int VV   = 50257;
constexpr int VPAD = 50304;   // V rounded up to 128
constexpr int NBX  = VPAD / 128; // lm_head col-blocks = 393
constexpr int MM   = BB * SS; // 2048 token rows

typedef unsigned short u16;
typedef short     s16x8 __attribute__((ext_vector_type(8)));
typedef float     f32x4 __attribute__((ext_vector_type(4)));
typedef u16       u16x4 __attribute__((ext_vector_type(4)));
typedef u16       u16x8 __attribute__((ext_vector_type(8)));

__device__ __forceinline__ float bf2f(u16 v) {
    return __uint_as_float(((unsigned)v) << 16);
}
__device__ __forceinline__ u16 f2bf(float f) {
    unsigned u = __float_as_uint(f);
    return (u16)((u + 0x7fffu + ((u >> 16) & 1u)) >> 16);
}

// ---------------- weight prep ----------------

// wte [V][C] f32 -> bf16 [VPAD][C], pad rows zero
__global__ __launch_bounds__(256) void wte_conv_kernel(const float* __restrict__ wte,
                                                       u16* __restrict__ out) {
    size_t i4 = ((size_t)blockIdx.x * 256 + threadIdx.x) * 4;
    if (i4 >= (size_t)VPAD * CC) return;
    size_t r = i4 / CC;
    u16x4 o;
    if (r < (size_t)VV) {
        const float4 v = *(const float4*)&wte[i4];
        o[0] = f2bf(v.x); o[1] = f2bf(v.y); o[2] = f2bf(v.z); o[3] = f2bf(v.w);
    } else {
        o[0] = o[1] = o[2] = o[3] = 0;
    }
    *(u16x4*)&out[i4] = o;
}

// in: [L][R][Cn] f32   out: [L][Cn][R] bf16   (R,Cn multiples of 32)
__global__ __launch_bounds__(256) void transpose_conv_kernel(const float* __restrict__ in,
                                                             u16* __restrict__ out,
                                                             int R, int Cn) {
    __shared__ float tile[32][33];
    const float* inp = in + (size_t)blockIdx.z * R * Cn;
    u16* outp = out + (size_t)blockIdx.z * R * Cn;
    int c  = blockIdx.x * 32 + threadIdx.x;
    int r0 = blockIdx.y * 32;
#pragma unroll
    for (int i = 0; i < 4; ++i) {
        int r = r0 + threadIdx.y + i * 8;
        tile[threadIdx.y + i * 8][threadIdx.x] = inp[(size_t)r * Cn + c];
    }
    __syncthreads();
    int oc = r0 + threadIdx.x; // output col = input row (k)
#pragma unroll
    for (int i = 0; i < 4; ++i) {
        int orow = blockIdx.x * 32 + threadIdx.y + i * 8; // output row (n)
        outp[(size_t)orow * R + oc] = f2bf(tile[threadIdx.x][threadIdx.y + i * 8]);
    }
}

// ---------------- embedding ----------------
__global__ __launch_bounds__(256) void embed_kernel(const int* __restrict__ idx,
                                                    const float* __restrict__ wte,
                                                    const float* __restrict__ wpe,
                                                    float* __restrict__ h) {
    int row = blockIdx.x;          // 0..2047
    int s   = row & (SS - 1);
    int tok = idx[row];
    const float* we = wte + (size_t)tok * CC;
    const float* pe = wpe + (size_t)s * CC;
    float* hr = h + (size_t)row * CC;
    for (int c = threadIdx.x; c < CC; c += 256) hr[c] = we[c] + pe[c];
}

// ---------------- layernorm: f32 in -> bf16 out ----------------
__global__ __launch_bounds__(256) void ln_kernel(const float* __restrict__ h,
                                                 const float* __restrict__ w,
                                                 const float* __restrict__ b,
                                                 u16* __restrict__ x) {
    int row = blockIdx.x, tid = threadIdx.x;
    const float* hr = h + (size_t)row * CC;
    float v0 = hr[tid], v1 = hr[tid + 256], v2 = hr[tid + 512];
    float s  = v0 + v1 + v2;
    float s2 = v0 * v0 + v1 * v1 + v2 * v2;
#pragma unroll
    for (int off = 32; off; off >>= 1) {
        s  += __shfl_xor(s, off);
        s2 += __shfl_xor(s2, off);
    }
    __shared__ float rs[4], rs2[4], stat[2];
    int wid = tid >> 6;
    if ((tid & 63) == 0) { rs[wid] = s; rs2[wid] = s2; }
    __syncthreads();
    if (tid == 0) {
        float ts  = rs[0] + rs[1] + rs[2] + rs[3];
        float ts2 = rs2[0] + rs2[1] + rs2[2] + rs2[3];
        float mean = ts * (1.0f / CC);
        float var  = ts2 * (1.0f / CC) - mean * mean;
        stat[0] = mean;
        stat[1] = rsqrtf(var + 1e-5f);
    }
    __syncthreads();
    float mean = stat[0], rstd = stat[1];
    size_t base = (size_t)row * CC;
    x[base + tid]       = f2bf((v0 - mean) * rstd * w[tid]       + b[tid]);
    x[base + tid + 256] = f2bf((v1 - mean) * rstd * w[tid + 256] + b[tid + 256]);
    x[base + tid + 512] = f2bf((v2 - mean) * rstd * w[tid + 512] + b[tid + 512]);
}

// ---------------- GEMM: C[M,N] = A[M,K] @ Bt[N,K]^T  (bf16 in, f32 acc) ----------------
// Reg-staged (global->VGPR->LDS), single 32KB LDS buffer, 2-barrier loop,
// T14 async split; LDS XOR chunk-swizzle both-sides (XOR within each 8-chunk
// half: phys = ((p&7)^(r&7)) | (p&8), an involution); XCD-chunked remap.
// BK=64 for 128x128 tiles (LDS 32KB); BK=128 for 64x64 tiles (LDS still 32KB,
// occupancy unchanged, barrier count halved — avoids m132's 128-tile trap).
// EPI: 0 = bias -> bf16 out        (qkv)
//      1 = bias+gelu -> bf16 out   (fc; gelu via overflow-safe sigmoid form)
//      2 = bias, residual add into f32 outf (proj, fc2)
//      3 = no bias, nontemporal f32 logits out (col<VV; NT keeps wteT in L3)
//          + per-block lse partials (lm_head)
template <int BM, int BN, int BK, int EPI>
__global__ __launch_bounds__(256)
void gemm_bt_kernel(const u16* __restrict__ A, const u16* __restrict__ Bt,
                    const float* __restrict__ bias, float* __restrict__ outf,
                    u16* __restrict__ outb, int K, long long ldo,
                    float* __restrict__ partM, float* __restrict__ partS) {
    constexpr int MR  = BM / 32, NR = BN / 32;   // fragment repeats per wave
    constexpr int ACH = BM * BK / (256 * 8);     // staged A chunks per thread
    constexpr int BCH = BN * BK / (256 * 8);
    constexpr int CPR = BK / 8;                  // 16B chunks per LDS row
    __shared__ u16 As[BM * BK];
    __shared__ u16 Bs[BN * BK];
    const int tid  = threadIdx.x;
    const int lane = tid & 63;
    const int wid  = tid >> 6;
    const int l15  = lane & 15;
    const int lq   = lane >> 4;
    const int wm   = wid & 1;
    const int wn   = wid >> 1;
    const int rx   = l15 & 7;                    // read-side XOR chunk term

    // XCD-chunked bijective remap; work id is column-major (bx outer, by inner)
    const int gx = gridDim.x, gy = gridDim.y;
    const int nwg = gx * gy;
    const int pos = blockIdx.y * gx + blockIdx.x;      // dispatch order
    const int qc  = nwg >> 3, rc = nwg & 7;
    const int xcd = pos & 7, cidx = pos >> 3;
    const int wgid = (xcd < rc ? xcd * (qc + 1) : rc * (qc + 1) + (xcd - rc) * qc) + cidx;
    const int bx = wgid / gy, by = wgid % gy;
    const int bm0 = by * BM, bn0 = bx * BN;

    f32x4 acc[MR][NR];
#pragma unroll
    for (int m = 0; m < MR; ++m)
#pragma unroll
        for (int n = 0; n < NR; ++n) acc[m][n] = (f32x4){0.f, 0.f, 0.f, 0.f};

    u16x8 areg[ACH], breg[BCH];
    auto ldreg = [&](int kt) {
#pragma unroll
        for (int it = 0; it < ACH; ++it) {
            int g = it * 256 + tid, r = g / CPR, p = g % CPR;
            int c = ((((p & 7) ^ (r & 7)) | (p & 8))) * 8;
            areg[it] = *(const u16x8*)&A[(size_t)(bm0 + r) * (size_t)K + kt + c];
        }
#pragma unroll
        for (int it = 0; it < BCH; ++it) {
            int g = it * 256 + tid, r = g / CPR, p = g % CPR;
            int c = ((((p & 7) ^ (r & 7)) | (p & 8))) * 8;
            breg[it] = *(const u16x8*)&Bt[(size_t)(bn0 + r) * (size_t)K + kt + c];
        }
    };
    auto wlds = [&]() {
#pragma unroll
        for (int it = 0; it < ACH; ++it) *(u16x8*)&As[(it * 256 + tid) * 8] = areg[it];
#pragma unroll
        for (int it = 0; it < BCH; ++it) *(u16x8*)&Bs[(it * 256 + tid) * 8] = breg[it];
    };
    auto compute = [&]() {
#pragma unroll
        for (int ks = 0; ks < BK / 32; ++ks) {
            const int ck = ks * 4 + lq;
            const int co = (((ck & 7) ^ rx) | (ck & 8)) * 8;
            s16x8 af[MR], bfr[NR];
#pragma unroll
            for (int m = 0; m < MR; ++m) {
                int row = wm * (BM / 2) + m * 16 + l15;
                af[m] = *(const s16x8*)&As[row * BK + co];
            }
#pragma unroll
            for (int n = 0; n < NR; ++n) {
                int row = wn * (BN / 2) + n * 16 + l15;
                bfr[n] = *(const s16x8*)&Bs[row * BK + co];
            }
#pragma unroll
            for (int m = 0; m < MR; ++m)
#pragma unroll
                for (int n = 0; n < NR; ++n)
                    acc[m][n] = __builtin_amdgcn_mfma_f32_16x16x32_bf16(af[m], bfr[n], acc[m][n], 0, 0, 0);
        }
    };

    const int nk = K / BK;
    ldreg(0);
    for (int t = 0; t < nk; ++t) {
        __syncthreads();          // previous compute done; LDS free
        wlds();
        __syncthreads();          // tile visible to all waves
        if (t + 1 < nk) ldreg((t + 1) * BK);  // issue next loads under compute
        compute();
    }

    // epilogue: C/D layout col=lane&15, row=4*(lane>>4)+reg
#pragma unroll
    for (int m = 0; m < MR; ++m) {
#pragma unroll
        for (int n = 0; n < NR; ++n) {
#pragma unroll
            for (int r = 0; r < 4; ++r) {
                int row = bm0 + wm * (BM / 2) + m * 16 + lq * 4 + r;
                int col = bn0 + wn * (BN / 2) + n * 16 + l15;
                float v = acc[m][n][r];
                if (EPI != 3) v += bias[col];
                if (EPI == 1) {
                    // gelu(tanh approx) == v * sigmoid(2*z); overflow-safe
                    float z = 0.7978845608028654f * (v + 0.044715f * v * v * v);
                    v = v / (1.0f + __expf(-2.0f * z));
                }
                if (EPI == 0 || EPI == 1) {
                    outb[(size_t)row * ldo + col] = f2bf(v);
                } else if (EPI == 2) {
                    outf[(size_t)row * ldo + col] += v;
                } else {
                    // nontemporal: logits are write-once; keep wteT resident in L3
                    if (col < VV) __builtin_nontemporal_store(v, &outf[(size_t)row * ldo + col]);
                }
            }
        }
    }

    // lm_head: per-row partial logsumexp over this block's BN cols
    if constexpr (EPI == 3) {
        __shared__ float redM[2][BM], redS[2][BM];
#pragma unroll
        for (int m = 0; m < MR; ++m) {
#pragma unroll
            for (int r = 0; r < 4; ++r) {
                float mx = -3.0e38f;
#pragma unroll
                for (int n = 0; n < NR; ++n) {
                    int colg = bn0 + wn * (BN / 2) + n * 16 + l15;
                    float v = (colg < VV) ? acc[m][n][r] : -3.0e38f;
                    mx = fmaxf(mx, v);
                }
#pragma unroll
                for (int off = 1; off < 16; off <<= 1) mx = fmaxf(mx, __shfl_xor(mx, off));
                float sm = 0.f;
#pragma unroll
                for (int n = 0; n < NR; ++n) {
                    int colg = bn0 + wn * (BN / 2) + n * 16 + l15;
                    if (colg < VV) sm += __expf(acc[m][n][r] - mx);
                }
#pragma unroll
                for (int off = 1; off < 16; off <<= 1) sm += __shfl_xor(sm, off);
                if (l15 == 0) {
                    int rl = wm * (BM / 2) + m * 16 + lq * 4 + r;
                    redM[wn][rl] = mx;
                    redS[wn][rl] = sm;
                }
            }
        }
        __syncthreads();
        if (tid < BM) {
            float m0 = redM[0][tid], m1 = redM[1][tid];
            float M = fmaxf(m0, m1);
            float S = redS[0][tid] * __expf(m0 - M) + redS[1][tid] * __expf(m1 - M);
            size_t rowg = (size_t)(bm0 + tid);
            partM[rowg * NBX + bx] = M;
            partS[rowg * NBX + bx] = S;
        }
    }
}

// ---------------- V transpose: qkv V-part [B][S][H*D] -> vT [B*H][D][S] ----------------
__global__ __launch_bounds__(256) void vtrans_kernel(const u16* __restrict__ qkv,
                                                     u16* __restrict__ vT) {
    __shared__ u16 T[64 * 64];
    const int tid = threadIdx.x;
    const int t0  = blockIdx.x * 64;
    const int bh  = blockIdx.y;
    const int b   = bh / HH, hh = bh % HH;
    const u16* vp = qkv + (size_t)b * SS * (3 * CC) + 2 * CC + hh * DD;
#pragma unroll
    for (int it = 0; it < 2; ++it) {
        int g = it * 256 + tid;
        int t = g >> 3, dg = g & 7;
        u16x8 v = *(const u16x8*)&vp[(size_t)(t0 + t) * (3 * CC) + dg * 8];
        *(u16x8*)&T[(t * 8 + (dg ^ (t & 7))) * 8] = v;
    }
    __syncthreads();
    u16* op = vT + (size_t)bh * DD * SS + t0;
#pragma unroll
    for (int it = 0; it < 2; ++it) {
        int g = it * 256 + tid;
        int d = g >> 3, tc = g & 7;
        u16x8 o;
#pragma unroll
        for (int e = 0; e < 8; ++e) {
            int t = tc * 8 + e;
            o[e] = T[(t * 8 + ((d >> 3) ^ (t & 7))) * 8 + (d & 7)];
        }
        *(u16x8*)&op[(size_t)d * SS + tc * 8] = o;
    }
}

// ---------------- MFMA flash attention v3.2 (T14 prefetch + T5 setprio) ----------------
// Block = one 64-row q-tile j of one (b,h); keys 0..j. 4 waves x 16 rows.
// grid = B*H*16 = 384; pos = (15-j)*24 + bh  ->  heavy tiles dispatch first,
// all 16 j-blocks of a bh share one XCD (24 % 8 == 0) for K/V L2 reuse.
__global__ __launch_bounds__(256) void attn_mfma3_kernel(const u16* __restrict__ qkv,
                                                         const u16* __restrict__ vT,
                                                         u16* __restrict__ o) {
    constexpr int PADC = 72;
    __shared__ u16 Ks[64][PADC];     // K[t][d]
    __shared__ u16 Vs[64][PADC];     // V^T[d][t]
    __shared__ u16 Ps[4][16][PADC];  // per-wave P tile [row][t]

    const int tid = threadIdx.x, lane = tid & 63, wid = tid >> 6;
    const int l15 = lane & 15, lq = lane >> 4;
    const int pos = blockIdx.x;                 // 0..383
    const int j   = 15 - pos / 24;              // q-tile index, heavy first
    const int bh  = pos % 24;
    const int b   = bh / HH, hh = bh % HH;
    const int q0  = j * 64;

    const size_t base = (size_t)b * SS * (3 * CC);
    const u16* kp = qkv + base + CC + hh * DD;
    const u16* vp = vT + (size_t)bh * DD * SS;

    s16x8 qf[2];
    {
        const u16* qr = qkv + base + hh * DD + (size_t)(q0 + wid * 16 + l15) * (3 * CC);
        qf[0] = *(const s16x8*)&qr[lq * 8];
        qf[1] = *(const s16x8*)&qr[32 + lq * 8];
    }

    float m[4], lsum[4];
    f32x4 acc_o[4];
#pragma unroll
    for (int r = 0; r < 4; ++r) { m[r] = -3.0e38f; lsum[r] = 0.f; }
#pragma unroll
    for (int nd = 0; nd < 4; ++nd) acc_o[nd] = (f32x4){0.f, 0.f, 0.f, 0.f};

    // per-thread staged K/V chunks (T14: load t+1 during compute of t)
    const int sr = tid >> 3, sc = (tid & 7) * 8;   // staging row / col for it=0
    const int sr1 = sr + 32;                        // it=1 covers rows 32..63
    u16x8 kreg[2], vreg[2];
    auto ldkv = [&](int t0) {
        kreg[0] = *(const u16x8*)&kp[(size_t)(t0 + sr) * (3 * CC) + sc];
        vreg[0] = *(const u16x8*)&vp[(size_t)sr * SS + t0 + sc];
        kreg[1] = *(const u16x8*)&kp[(size_t)(t0 + sr1) * (3 * CC) + sc];
        vreg[1] = *(const u16x8*)&vp[(size_t)sr1 * SS + t0 + sc];
    };

    ldkv(0);
    for (int tt = 0; tt <= j; ++tt) {
        __syncthreads();   // all waves done reading previous K/V tiles
        *(u16x8*)&Ks[sr][sc]  = kreg[0];
        *(u16x8*)&Vs[sr][sc]  = vreg[0];
        *(u16x8*)&Ks[sr1][sc] = kreg[1];
        *(u16x8*)&Vs[sr1][sc] = vreg[1];
        __syncthreads();
        if (tt < j) ldkv((tt + 1) * 64);  // issue next tile's loads under compute

        // QK^T (T5: boost wave priority through the MFMA cluster)
        f32x4 sc4[4];
#pragma unroll
        for (int n = 0; n < 4; ++n) sc4[n] = (f32x4){0.f, 0.f, 0.f, 0.f};
        __builtin_amdgcn_s_setprio(1);
#pragma unroll
        for (int ks = 0; ks < 2; ++ks) {
#pragma unroll
            for (int n = 0; n < 4; ++n) {
                s16x8 kb = *(const s16x8*)&Ks[n * 16 + l15][ks * 32 + lq * 8];
                sc4[n] = __builtin_amdgcn_mfma_f32_16x16x32_bf16(qf[ks], kb, sc4[n], 0, 0, 0);
            }
        }
        __builtin_amdgcn_s_setprio(0);

        const int t0 = tt * 64;
        if (tt == j) {
#pragma unroll
            for (int n = 0; n < 4; ++n) {
                int colg = t0 + n * 16 + l15;
#pragma unroll
                for (int r = 0; r < 4; ++r) {
                    int rowg = q0 + wid * 16 + lq * 4 + r;
                    float sv = sc4[n][r] * 0.125f;
                    sc4[n][r] = (colg <= rowg) ? sv : -3.0e38f;
                }
            }
        } else {
#pragma unroll
            for (int n = 0; n < 4; ++n)
#pragma unroll
                for (int r = 0; r < 4; ++r) sc4[n][r] *= 0.125f;
        }

        // online softmax
        float mt[4];
#pragma unroll
        for (int r = 0; r < 4; ++r)
            mt[r] = fmaxf(fmaxf(sc4[0][r], sc4[1][r]), fmaxf(sc4[2][r], sc4[3][r]));
#pragma unroll
        for (int off = 1; off < 16; off <<= 1)
#pragma unroll
            for (int r = 0; r < 4; ++r) mt[r] = fmaxf(mt[r], __shfl_xor(mt[r], off));
        float rs[4];
#pragma unroll
        for (int r = 0; r < 4; ++r) {
            float mn  = fmaxf(m[r], mt[r]);
            float scl = __expf(m[r] - mn);
            m[r] = mn;
            float ps = 0.f;
#pragma unroll
            for (int n = 0; n < 4; ++n) {
                float p = __expf(sc4[n][r] - mn);
                sc4[n][r] = p;
                ps += p;
            }
            rs[r] = ps;
            lsum[r] *= scl;
#pragma unroll
            for (int nd = 0; nd < 4; ++nd) acc_o[nd][r] *= scl;
        }
#pragma unroll
        for (int off = 1; off < 16; off <<= 1)
#pragma unroll
            for (int r = 0; r < 4; ++r) rs[r] += __shfl_xor(rs[r], off);
#pragma unroll
        for (int r = 0; r < 4; ++r) lsum[r] += rs[r];

        // P -> LDS (wave-private; no barrier needed before PV reads)
#pragma unroll
        for (int n = 0; n < 4; ++n)
#pragma unroll
            for (int r = 0; r < 4; ++r)
                Ps[wid][lq * 4 + r][n * 16 + l15] = f2bf(sc4[n][r]);

        // PV (T5)
        __builtin_amdgcn_s_setprio(1);
#pragma unroll
        for (int ks = 0; ks < 2; ++ks) {
            s16x8 pa = *(const s16x8*)&Ps[wid][l15][ks * 32 + lq * 8];
#pragma unroll
            for (int nd = 0; nd < 4; ++nd) {
                s16x8 vb = *(const s16x8*)&Vs[nd * 16 + l15][ks * 32 + lq * 8];
                acc_o[nd] = __builtin_amdgcn_mfma_f32_16x16x32_bf16(pa, vb, acc_o[nd], 0, 0, 0);
            }
        }
        __builtin_amdgcn_s_setprio(0);
    }

#pragma unroll
    for (int r = 0; r < 4; ++r) {
        float inv = 1.f / lsum[r];
        int rowg = q0 + wid * 16 + lq * 4 + r;
        u16* orow = o + ((size_t)b * SS + rowg) * CC + hh * DD;
#pragma unroll
        for (int nd = 0; nd < 4; ++nd)
            orow[nd * 16 + l15] = f2bf(acc_o[nd][r] * inv);
    }
}

// ---------------- loss (from lm_head partials) ----------------
__global__ __launch_bounds__(256) void lse_kernel(const float* __restrict__ partM,
                                                  const float* __restrict__ partS,
                                                  const float* __restrict__ logits,
                                                  const int* __restrict__ tgt,
                                                  float* __restrict__ lossp) {
    int row = blockIdx.x, tid = threadIdx.x;
    float m = -3.0e38f, s = 0.f;
    for (int i = tid; i < NBX; i += 256) {
        float pm = partM[(size_t)row * NBX + i];
        float ps = partS[(size_t)row * NBX + i];
        float nm = fmaxf(m, pm);
        s = s * __expf(m - nm) + ps * __expf(pm - nm);
        m = nm;
    }
#pragma unroll
    for (int off = 32; off; off >>= 1) {
        float om = __shfl_xor(m, off), os = __shfl_xor(s, off);
        float nm = fmaxf(m, om);
        s = s * __expf(m - nm) + os * __expf(om - nm);
        m = nm;
    }
    __shared__ float rm[4], rsh[4];
    int wid = tid >> 6;
    if ((tid & 63) == 0) { rm[wid] = m; rsh[wid] = s; }
    __syncthreads();
    if (tid == 0) {
        float M = fmaxf(fmaxf(rm[0], rm[1]), fmaxf(rm[2], rm[3]));
        float S = rsh[0] * __expf(rm[0] - M) + rsh[1] * __expf(rm[1] - M) +
                  rsh[2] * __expf(rm[2] - M) + rsh[3] * __expf(rm[3] - M);
        float lse = M + __logf(S);
        lossp[row] = lse - logits[(size_t)row * VV + tgt[row]];
    }
}

__global__ __launch_bounds__(256) void loss_reduce_kernel(const float* __restrict__ lossp,
                                                          float* __restrict__ out) {
    int tid = threadIdx.x;
    float s = 0.f;
    for (int i = tid; i < MM; i += 256) s += lossp[i];
#pragma unroll
    for (int off = 32; off; off >>= 1) s += __shfl_xor(s, off);
    __shared__ float r[4];
    if ((tid & 63) == 0) r[tid >> 6] = s;
    __syncthreads();
    if (tid == 0) out[0] = (r[0] + r[1] + r[2] + r[3]) * (1.0f / MM);
}

// ---------------- host ----------------
extern "C" void kernel_launch(void* const* d_in, const int* in_sizes, int n_in,
                              void* d_out, int out_size, void* d_ws, size_t ws_size,
                              hipStream_t stream) {
    const int*   idx     = (const int*)  d_in[0];
    const int*   targets = (const int*)  d_in[1];
    const float* wte     = (const float*)d_in[2];
    const float* wpe     = (const float*)d_in[3];
    const float* ln1w    = (const float*)d_in[4];
    const float* ln1b    = (const float*)d_in[5];
    const float* qkvw    = (const float*)d_in[6];
    const float* qkvbi   = (const float*)d_in[7];
    const float* projw   = (const float*)d_in[8];
    const float* projbi  = (const float*)d_in[9];
    const float* ln2w    = (const float*)d_in[10];
    const float* ln2b    = (const float*)d_in[11];
    const float* fcw     = (const float*)d_in[12];
    const float* fcbi    = (const float*)d_in[13];
    const float* fc2w    = (const float*)d_in[14];
    const float* fc2bi   = (const float*)d_in[15];
    const float* lnfw    = (const float*)d_in[16];
    const float* lnfb    = (const float*)d_in[17];
    float* logits = (float*)d_out;

    char* wsb = (char*)d_ws;
    size_t off = 0;
    auto alloc = [&](size_t n) -> char* {
        char* p = wsb + off;
        off = (off + n + 255) & ~(size_t)255;
        return p;
    };
    u16*   wteT  = (u16*)  alloc((size_t)VPAD * CC * 2);
    u16*   qkvT  = (u16*)  alloc((size_t)LNUM * 3 * CC * CC * 2);
    u16*   projT = (u16*)  alloc((size_t)LNUM * CC * CC * 2);
    u16*   fcT   = (u16*)  alloc((size_t)LNUM * FFD * CC * 2);
    u16*   fc2T  = (u16*)  alloc((size_t)LNUM * CC * FFD * 2);
    float* h     = (float*)alloc((size_t)MM * CC * 4);
    u16*   xb    = (u16*)  alloc((size_t)MM * CC * 2);
    u16*   qkvb  = (u16*)  alloc((size_t)MM * 3 * CC * 2);
    u16*   ob    = (u16*)  alloc((size_t)MM * CC * 2);
    u16*   gb    = (u16*)  alloc((size_t)MM * FFD * 2);
    u16*   vTb   = (u16*)  alloc((size_t)BB * HH * DD * SS * 2);
    float* lossp = (float*)alloc((size_t)MM * 4);
    float* partM = (float*)alloc((size_t)MM * NBX * 4);
    float* partS = (float*)alloc((size_t)MM * NBX * 4);

    // weight prep
    {
        int blocks = (int)(((size_t)VPAD * CC / 4 + 255) / 256);
        wte_conv_kernel<<<blocks, 256, 0, stream>>>(wte, wteT);
    }
    transpose_conv_kernel<<<dim3(3 * CC / 32, CC / 32, LNUM), dim3(32, 8), 0, stream>>>(qkvw, qkvT, CC, 3 * CC);
    transpose_conv_kernel<<<dim3(CC / 32, CC / 32, LNUM),     dim3(32, 8), 0, stream>>>(projw, projT, CC, CC);
    transpose_conv_kernel<<<dim3(FFD / 32, CC / 32, LNUM),    dim3(32, 8), 0, stream>>>(fcw, fcT, CC, FFD);
    transpose_conv_kernel<<<dim3(CC / 32, FFD / 32, LNUM),    dim3(32, 8), 0, stream>>>(fc2w, fc2T, FFD, CC);

    embed_kernel<<<MM, 256, 0, stream>>>(idx, wte, wpe, h);

    for (int l = 0; l < LNUM; ++l) {
        const u16* qkvT_l  = qkvT  + (size_t)l * 3 * CC * CC;
        const u16* projT_l = projT + (size_t)l * CC * CC;
        const u16* fcT_l   = fcT   + (size_t)l * FFD * CC;
        const u16* fc2T_l  = fc2T  + (size_t)l * CC * FFD;

        ln_kernel<<<MM, 256, 0, stream>>>(h, ln1w + (size_t)l * CC, ln1b + (size_t)l * CC, xb);
        gemm_bt_kernel<128, 128, 64, 0><<<dim3(3 * CC / 128, MM / 128), 256, 0, stream>>>(
            xb, qkvT_l, qkvbi + (size_t)l * 3 * CC, nullptr, qkvb, CC, 3 * CC, nullptr, nullptr);
        vtrans_kernel<<<dim3(SS / 64, BB * HH), 256, 0, stream>>>(qkvb, vTb);
        attn_mfma3_kernel<<<BB * HH * 16, 256, 0, stream>>>(qkvb, vTb, ob);
        gemm_bt_kernel<64, 64, 128, 2><<<dim3(CC / 64, MM / 64), 256, 0, stream>>>(
            ob, projT_l, projbi + (size_t)l * CC, h, nullptr, CC, CC, nullptr, nullptr);
        ln_kernel<<<MM, 256, 0, stream>>>(h, ln2w + (size_t)l * CC, ln2b + (size_t)l * CC, xb);
        gemm_bt_kernel<128, 128, 64, 1><<<dim3(FFD / 128, MM / 128), 256, 0, stream>>>(
            xb, fcT_l, fcbi + (size_t)l * FFD, nullptr, gb, CC, FFD, nullptr, nullptr);
        gemm_bt_kernel<64, 64, 128, 2><<<dim3(CC / 64, MM / 64), 256, 0, stream>>>(
            gb, fc2T_l, fc2bi + (size_t)l * CC, h, nullptr, FFD, CC, nullptr, nullptr);
    }

    ln_kernel<<<MM, 256, 0, stream>>>(h, lnfw, lnfb, xb);
    gemm_bt_kernel<128, 128, 64, 3><<<dim3(VPAD / 128, MM / 128), 256, 0, stream>>>(
        xb, wteT, nullptr, logits, nullptr, CC, VV, partM, partS);

    lse_kernel<<<MM, 256, 0, stream>>>(partM, partS, logits, targets, lossp);
    loss_reduce_kernel<<<1, 256, 0, stream>>>(lossp, logits + (size_t)MM * VV);
}

// Round 13
// 1932.637 us; speedup vs baseline: 1.0739x; 1.0739x over previous
//
#include <hip/hip_runtime.h>
#include <hip/hip_bf16.h>
#include <cstdint>
#include <cstddef>

// ---- model dims ----
constexpr int LNUM = 12;
constexpr int BB   = 2;
constexpr int SS   = 1024;
constexpr int CC   = 768;
constexpr int HH   = 12;
constexpr int DD   = 64;      // C/H
constexpr int FFD  = 3072;    // 4C
constexpr int VV   = 50257;
constexpr int VPAD = 50304;   // V rounded up to 128
constexpr int NBX  = VPAD / 128; // lm_head col-blocks = 393
constexpr int MM   = BB * SS; // 2048 token rows

typedef unsigned short u16;
typedef short     s16x8 __attribute__((ext_vector_type(8)));
typedef float     f32x4 __attribute__((ext_vector_type(4)));
typedef u16       u16x4 __attribute__((ext_vector_type(4)));
typedef u16       u16x8 __attribute__((ext_vector_type(8)));

__device__ __forceinline__ float bf2f(u16 v) {
    return __uint_as_float(((unsigned)v) << 16);
}
__device__ __forceinline__ u16 f2bf(float f) {
    unsigned u = __float_as_uint(f);
    return (u16)((u + 0x7fffu + ((u >> 16) & 1u)) >> 16);
}

// ---------------- weight prep ----------------

// wte [V][C] f32 -> bf16 [VPAD][C], pad rows zero
__global__ __launch_bounds__(256) void wte_conv_kernel(const float* __restrict__ wte,
                                                       u16* __restrict__ out) {
    size_t i4 = ((size_t)blockIdx.x * 256 + threadIdx.x) * 4;
    if (i4 >= (size_t)VPAD * CC) return;
    size_t r = i4 / CC;
    u16x4 o;
    if (r < (size_t)VV) {
        const float4 v = *(const float4*)&wte[i4];
        o[0] = f2bf(v.x); o[1] = f2bf(v.y); o[2] = f2bf(v.z); o[3] = f2bf(v.w);
    } else {
        o[0] = o[1] = o[2] = o[3] = 0;
    }
    *(u16x4*)&out[i4] = o;
}

// in: [L][R][Cn] f32   out: [L][Cn][R] bf16   (R,Cn multiples of 32)
__global__ __launch_bounds__(256) void transpose_conv_kernel(const float* __restrict__ in,
                                                             u16* __restrict__ out,
                                                             int R, int Cn) {
    __shared__ float tile[32][33];
    const float* inp = in + (size_t)blockIdx.z * R * Cn;
    u16* outp = out + (size_t)blockIdx.z * R * Cn;
    int c  = blockIdx.x * 32 + threadIdx.x;
    int r0 = blockIdx.y * 32;
#pragma unroll
    for (int i = 0; i < 4; ++i) {
        int r = r0 + threadIdx.y + i * 8;
        tile[threadIdx.y + i * 8][threadIdx.x] = inp[(size_t)r * Cn + c];
    }
    __syncthreads();
    int oc = r0 + threadIdx.x; // output col = input row (k)
#pragma unroll
    for (int i = 0; i < 4; ++i) {
        int orow = blockIdx.x * 32 + threadIdx.y + i * 8; // output row (n)
        outp[(size_t)orow * R + oc] = f2bf(tile[threadIdx.x][threadIdx.y + i * 8]);
    }
}

// ---------------- embedding ----------------
__global__ __launch_bounds__(256) void embed_kernel(const int* __restrict__ idx,
                                                    const float* __restrict__ wte,
                                                    const float* __restrict__ wpe,
                                                    float* __restrict__ h) {
    int row = blockIdx.x;          // 0..2047
    int s   = row & (SS - 1);
    int tok = idx[row];
    const float* we = wte + (size_t)tok * CC;
    const float* pe = wpe + (size_t)s * CC;
    float* hr = h + (size_t)row * CC;
    for (int c = threadIdx.x; c < CC; c += 256) hr[c] = we[c] + pe[c];
}

// ---------------- layernorm: f32 in -> bf16 out ----------------
__global__ __launch_bounds__(256) void ln_kernel(const float* __restrict__ h,
                                                 const float* __restrict__ w,
                                                 const float* __restrict__ b,
                                                 u16* __restrict__ x) {
    int row = blockIdx.x, tid = threadIdx.x;
    const float* hr = h + (size_t)row * CC;
    float v0 = hr[tid], v1 = hr[tid + 256], v2 = hr[tid + 512];
    float s  = v0 + v1 + v2;
    float s2 = v0 * v0 + v1 * v1 + v2 * v2;
#pragma unroll
    for (int off = 32; off; off >>= 1) {
        s  += __shfl_xor(s, off);
        s2 += __shfl_xor(s2, off);
    }
    __shared__ float rs[4], rs2[4], stat[2];
    int wid = tid >> 6;
    if ((tid & 63) == 0) { rs[wid] = s; rs2[wid] = s2; }
    __syncthreads();
    if (tid == 0) {
        float ts  = rs[0] + rs[1] + rs[2] + rs[3];
        float ts2 = rs2[0] + rs2[1] + rs2[2] + rs2[3];
        float mean = ts * (1.0f / CC);
        float var  = ts2 * (1.0f / CC) - mean * mean;
        stat[0] = mean;
        stat[1] = rsqrtf(var + 1e-5f);
    }
    __syncthreads();
    float mean = stat[0], rstd = stat[1];
    size_t base = (size_t)row * CC;
    x[base + tid]       = f2bf((v0 - mean) * rstd * w[tid]       + b[tid]);
    x[base + tid + 256] = f2bf((v1 - mean) * rstd * w[tid + 256] + b[tid + 256]);
    x[base + tid + 512] = f2bf((v2 - mean) * rstd * w[tid + 512] + b[tid + 512]);
}

// ---------------- GEMM: C[M,N] = A[M,K] @ Bt[N,K]^T  (bf16 in, f32 acc) ----------------
// Reg-staged (global->VGPR->LDS), single 32KB LDS buffer, 2-barrier loop,
// T14 async split; LDS XOR chunk-swizzle both-sides (XOR within each 8-chunk
// half: phys = ((p&7)^(r&7)) | (p&8), an involution); XCD-chunked remap.
// BK=64 for 128x128 tiles (LDS 32KB); BK=128 for 64x64 tiles (LDS still 32KB,
// occupancy unchanged, barrier count halved).
// EPI: 0 = bias -> bf16 out        (qkv)
//      1 = bias+gelu -> bf16 out   (fc; gelu via overflow-safe sigmoid form)
//      2 = bias, residual add into f32 outf (proj, fc2)
//      3 = no bias, f32 logits out (col<VV; regular cached store — NT store
//          doubles HBM writes via partial-line bypass, r12 measured) + partials
template <int BM, int BN, int BK, int EPI>
__global__ __launch_bounds__(256)
void gemm_bt_kernel(const u16* __restrict__ A, const u16* __restrict__ Bt,
                    const float* __restrict__ bias, float* __restrict__ outf,
                    u16* __restrict__ outb, int K, long long ldo,
                    float* __restrict__ partM, float* __restrict__ partS) {
    constexpr int MR  = BM / 32, NR = BN / 32;   // fragment repeats per wave
    constexpr int ACH = BM * BK / (256 * 8);     // staged A chunks per thread
    constexpr int BCH = BN * BK / (256 * 8);
    constexpr int CPR = BK / 8;                  // 16B chunks per LDS row
    __shared__ u16 As[BM * BK];
    __shared__ u16 Bs[BN * BK];
    const int tid  = threadIdx.x;
    const int lane = tid & 63;
    const int wid  = tid >> 6;
    const int l15  = lane & 15;
    const int lq   = lane >> 4;
    const int wm   = wid & 1;
    const int wn   = wid >> 1;
    const int rx   = l15 & 7;                    // read-side XOR chunk term

    // XCD-chunked bijective remap; work id is column-major (bx outer, by inner)
    const int gx = gridDim.x, gy = gridDim.y;
    const int nwg = gx * gy;
    const int pos = blockIdx.y * gx + blockIdx.x;      // dispatch order
    const int qc  = nwg >> 3, rc = nwg & 7;
    const int xcd = pos & 7, cidx = pos >> 3;
    const int wgid = (xcd < rc ? xcd * (qc + 1) : rc * (qc + 1) + (xcd - rc) * qc) + cidx;
    const int bx = wgid / gy, by = wgid % gy;
    const int bm0 = by * BM, bn0 = bx * BN;

    f32x4 acc[MR][NR];
#pragma unroll
    for (int m = 0; m < MR; ++m)
#pragma unroll
        for (int n = 0; n < NR; ++n) acc[m][n] = (f32x4){0.f, 0.f, 0.f, 0.f};

    u16x8 areg[ACH], breg[BCH];
    auto ldreg = [&](int kt) {
#pragma unroll
        for (int it = 0; it < ACH; ++it) {
            int g = it * 256 + tid, r = g / CPR, p = g % CPR;
            int c = ((((p & 7) ^ (r & 7)) | (p & 8))) * 8;
            areg[it] = *(const u16x8*)&A[(size_t)(bm0 + r) * (size_t)K + kt + c];
        }
#pragma unroll
        for (int it = 0; it < BCH; ++it) {
            int g = it * 256 + tid, r = g / CPR, p = g % CPR;
            int c = ((((p & 7) ^ (r & 7)) | (p & 8))) * 8;
            breg[it] = *(const u16x8*)&Bt[(size_t)(bn0 + r) * (size_t)K + kt + c];
        }
    };
    auto wlds = [&]() {
#pragma unroll
        for (int it = 0; it < ACH; ++it) *(u16x8*)&As[(it * 256 + tid) * 8] = areg[it];
#pragma unroll
        for (int it = 0; it < BCH; ++it) *(u16x8*)&Bs[(it * 256 + tid) * 8] = breg[it];
    };
    auto compute = [&]() {
#pragma unroll
        for (int ks = 0; ks < BK / 32; ++ks) {
            const int ck = ks * 4 + lq;
            const int co = (((ck & 7) ^ rx) | (ck & 8)) * 8;
            s16x8 af[MR], bfr[NR];
#pragma unroll
            for (int m = 0; m < MR; ++m) {
                int row = wm * (BM / 2) + m * 16 + l15;
                af[m] = *(const s16x8*)&As[row * BK + co];
            }
#pragma unroll
            for (int n = 0; n < NR; ++n) {
                int row = wn * (BN / 2) + n * 16 + l15;
                bfr[n] = *(const s16x8*)&Bs[row * BK + co];
            }
#pragma unroll
            for (int m = 0; m < MR; ++m)
#pragma unroll
                for (int n = 0; n < NR; ++n)
                    acc[m][n] = __builtin_amdgcn_mfma_f32_16x16x32_bf16(af[m], bfr[n], acc[m][n], 0, 0, 0);
        }
    };

    const int nk = K / BK;
    ldreg(0);
    for (int t = 0; t < nk; ++t) {
        __syncthreads();          // previous compute done; LDS free
        wlds();
        __syncthreads();          // tile visible to all waves
        if (t + 1 < nk) ldreg((t + 1) * BK);  // issue next loads under compute
        compute();
    }

    // epilogue: C/D layout col=lane&15, row=4*(lane>>4)+reg
#pragma unroll
    for (int m = 0; m < MR; ++m) {
#pragma unroll
        for (int n = 0; n < NR; ++n) {
#pragma unroll
            for (int r = 0; r < 4; ++r) {
                int row = bm0 + wm * (BM / 2) + m * 16 + lq * 4 + r;
                int col = bn0 + wn * (BN / 2) + n * 16 + l15;
                float v = acc[m][n][r];
                if (EPI != 3) v += bias[col];
                if (EPI == 1) {
                    // gelu(tanh approx) == v * sigmoid(2*z); overflow-safe
                    float z = 0.7978845608028654f * (v + 0.044715f * v * v * v);
                    v = v / (1.0f + __expf(-2.0f * z));
                }
                if (EPI == 0 || EPI == 1) {
                    outb[(size_t)row * ldo + col] = f2bf(v);
                } else if (EPI == 2) {
                    outf[(size_t)row * ldo + col] += v;
                } else {
                    if (col < VV) outf[(size_t)row * ldo + col] = v;
                }
            }
        }
    }

    // lm_head: per-row partial logsumexp over this block's BN cols
    if constexpr (EPI == 3) {
        __shared__ float redM[2][BM], redS[2][BM];
#pragma unroll
        for (int m = 0; m < MR; ++m) {
#pragma unroll
            for (int r = 0; r < 4; ++r) {
                float mx = -3.0e38f;
#pragma unroll
                for (int n = 0; n < NR; ++n) {
                    int colg = bn0 + wn * (BN / 2) + n * 16 + l15;
                    float v = (colg < VV) ? acc[m][n][r] : -3.0e38f;
                    mx = fmaxf(mx, v);
                }
#pragma unroll
                for (int off = 1; off < 16; off <<= 1) mx = fmaxf(mx, __shfl_xor(mx, off));
                float sm = 0.f;
#pragma unroll
                for (int n = 0; n < NR; ++n) {
                    int colg = bn0 + wn * (BN / 2) + n * 16 + l15;
                    if (colg < VV) sm += __expf(acc[m][n][r] - mx);
                }
#pragma unroll
                for (int off = 1; off < 16; off <<= 1) sm += __shfl_xor(sm, off);
                if (l15 == 0) {
                    int rl = wm * (BM / 2) + m * 16 + lq * 4 + r;
                    redM[wn][rl] = mx;
                    redS[wn][rl] = sm;
                }
            }
        }
        __syncthreads();
        if (tid < BM) {
            float m0 = redM[0][tid], m1 = redM[1][tid];
            float M = fmaxf(m0, m1);
            float S = redS[0][tid] * __expf(m0 - M) + redS[1][tid] * __expf(m1 - M);
            size_t rowg = (size_t)(bm0 + tid);
            partM[rowg * NBX + bx] = M;
            partS[rowg * NBX + bx] = S;
        }
    }
}

// ---------------- V transpose: qkv V-part [B][S][H*D] -> vT [B*H][D][S] ----------------
__global__ __launch_bounds__(256) void vtrans_kernel(const u16* __restrict__ qkv,
                                                     u16* __restrict__ vT) {
    __shared__ u16 T[64 * 64];
    const int tid = threadIdx.x;
    const int t0  = blockIdx.x * 64;
    const int bh  = blockIdx.y;
    const int b   = bh / HH, hh = bh % HH;
    const u16* vp = qkv + (size_t)b * SS * (3 * CC) + 2 * CC + hh * DD;
#pragma unroll
    for (int it = 0; it < 2; ++it) {
        int g = it * 256 + tid;
        int t = g >> 3, dg = g & 7;
        u16x8 v = *(const u16x8*)&vp[(size_t)(t0 + t) * (3 * CC) + dg * 8];
        *(u16x8*)&T[(t * 8 + (dg ^ (t & 7))) * 8] = v;
    }
    __syncthreads();
    u16* op = vT + (size_t)bh * DD * SS + t0;
#pragma unroll
    for (int it = 0; it < 2; ++it) {
        int g = it * 256 + tid;
        int d = g >> 3, tc = g & 7;
        u16x8 o;
#pragma unroll
        for (int e = 0; e < 8; ++e) {
            int t = tc * 8 + e;
            o[e] = T[(t * 8 + ((d >> 3) ^ (t & 7))) * 8 + (d & 7)];
        }
        *(u16x8*)&op[(size_t)d * SS + tc * 8] = o;
    }
}

// ---------------- MFMA flash attention v3.2 (T14 prefetch + T5 setprio) ----------------
// Block = one 64-row q-tile j of one (b,h); keys 0..j. 4 waves x 16 rows.
// grid = B*H*16 = 384; pos = (15-j)*24 + bh  ->  heavy tiles dispatch first,
// all 16 j-blocks of a bh share one XCD (24 % 8 == 0) for K/V L2 reuse.
__global__ __launch_bounds__(256) void attn_mfma3_kernel(const u16* __restrict__ qkv,
                                                         const u16* __restrict__ vT,
                                                         u16* __restrict__ o) {
    constexpr int PADC = 72;
    __shared__ u16 Ks[64][PADC];     // K[t][d]
    __shared__ u16 Vs[64][PADC];     // V^T[d][t]
    __shared__ u16 Ps[4][16][PADC];  // per-wave P tile [row][t]

    const int tid = threadIdx.x, lane = tid & 63, wid = tid >> 6;
    const int l15 = lane & 15, lq = lane >> 4;
    const int pos = blockIdx.x;                 // 0..383
    const int j   = 15 - pos / 24;              // q-tile index, heavy first
    const int bh  = pos % 24;
    const int b   = bh / HH, hh = bh % HH;
    const int q0  = j * 64;

    const size_t base = (size_t)b * SS * (3 * CC);
    const u16* kp = qkv + base + CC + hh * DD;
    const u16* vp = vT + (size_t)bh * DD * SS;

    s16x8 qf[2];
    {
        const u16* qr = qkv + base + hh * DD + (size_t)(q0 + wid * 16 + l15) * (3 * CC);
        qf[0] = *(const s16x8*)&qr[lq * 8];
        qf[1] = *(const s16x8*)&qr[32 + lq * 8];
    }

    float m[4], lsum[4];
    f32x4 acc_o[4];
#pragma unroll
    for (int r = 0; r < 4; ++r) { m[r] = -3.0e38f; lsum[r] = 0.f; }
#pragma unroll
    for (int nd = 0; nd < 4; ++nd) acc_o[nd] = (f32x4){0.f, 0.f, 0.f, 0.f};

    // per-thread staged K/V chunks (T14: load t+1 during compute of t)
    const int sr = tid >> 3, sc = (tid & 7) * 8;   // staging row / col for it=0
    const int sr1 = sr + 32;                        // it=1 covers rows 32..63
    u16x8 kreg[2], vreg[2];
    auto ldkv = [&](int t0) {
        kreg[0] = *(const u16x8*)&kp[(size_t)(t0 + sr) * (3 * CC) + sc];
        vreg[0] = *(const u16x8*)&vp[(size_t)sr * SS + t0 + sc];
        kreg[1] = *(const u16x8*)&kp[(size_t)(t0 + sr1) * (3 * CC) + sc];
        vreg[1] = *(const u16x8*)&vp[(size_t)sr1 * SS + t0 + sc];
    };

    ldkv(0);
    for (int tt = 0; tt <= j; ++tt) {
        __syncthreads();   // all waves done reading previous K/V tiles
        *(u16x8*)&Ks[sr][sc]  = kreg[0];
        *(u16x8*)&Vs[sr][sc]  = vreg[0];
        *(u16x8*)&Ks[sr1][sc] = kreg[1];
        *(u16x8*)&Vs[sr1][sc] = vreg[1];
        __syncthreads();
        if (tt < j) ldkv((tt + 1) * 64);  // issue next tile's loads under compute

        // QK^T (T5: boost wave priority through the MFMA cluster)
        f32x4 sc4[4];
#pragma unroll
        for (int n = 0; n < 4; ++n) sc4[n] = (f32x4){0.f, 0.f, 0.f, 0.f};
        __builtin_amdgcn_s_setprio(1);
#pragma unroll
        for (int ks = 0; ks < 2; ++ks) {
#pragma unroll
            for (int n = 0; n < 4; ++n) {
                s16x8 kb = *(const s16x8*)&Ks[n * 16 + l15][ks * 32 + lq * 8];
                sc4[n] = __builtin_amdgcn_mfma_f32_16x16x32_bf16(qf[ks], kb, sc4[n], 0, 0, 0);
            }
        }
        __builtin_amdgcn_s_setprio(0);

        const int t0 = tt * 64;
        if (tt == j) {
#pragma unroll
            for (int n = 0; n < 4; ++n) {
                int colg = t0 + n * 16 + l15;
#pragma unroll
                for (int r = 0; r < 4; ++r) {
                    int rowg = q0 + wid * 16 + lq * 4 + r;
                    float sv = sc4[n][r] * 0.125f;
                    sc4[n][r] = (colg <= rowg) ? sv : -3.0e38f;
                }
            }
        } else {
#pragma unroll
            for (int n = 0; n < 4; ++n)
#pragma unroll
                for (int r = 0; r < 4; ++r) sc4[n][r] *= 0.125f;
        }

        // online softmax
        float mt[4];
#pragma unroll
        for (int r = 0; r < 4; ++r)
            mt[r] = fmaxf(fmaxf(sc4[0][r], sc4[1][r]), fmaxf(sc4[2][r], sc4[3][r]));
#pragma unroll
        for (int off = 1; off < 16; off <<= 1)
#pragma unroll
            for (int r = 0; r < 4; ++r) mt[r] = fmaxf(mt[r], __shfl_xor(mt[r], off));
        float rs[4];
#pragma unroll
        for (int r = 0; r < 4; ++r) {
            float mn  = fmaxf(m[r], mt[r]);
            float scl = __expf(m[r] - mn);
            m[r] = mn;
            float ps = 0.f;
#pragma unroll
            for (int n = 0; n < 4; ++n) {
                float p = __expf(sc4[n][r] - mn);
                sc4[n][r] = p;
                ps += p;
            }
            rs[r] = ps;
            lsum[r] *= scl;
#pragma unroll
            for (int nd = 0; nd < 4; ++nd) acc_o[nd][r] *= scl;
        }
#pragma unroll
        for (int off = 1; off < 16; off <<= 1)
#pragma unroll
            for (int r = 0; r < 4; ++r) rs[r] += __shfl_xor(rs[r], off);
#pragma unroll
        for (int r = 0; r < 4; ++r) lsum[r] += rs[r];

        // P -> LDS (wave-private; no barrier needed before PV reads)
#pragma unroll
        for (int n = 0; n < 4; ++n)
#pragma unroll
            for (int r = 0; r < 4; ++r)
                Ps[wid][lq * 4 + r][n * 16 + l15] = f2bf(sc4[n][r]);

        // PV (T5)
        __builtin_amdgcn_s_setprio(1);
#pragma unroll
        for (int ks = 0; ks < 2; ++ks) {
            s16x8 pa = *(const s16x8*)&Ps[wid][l15][ks * 32 + lq * 8];
#pragma unroll
            for (int nd = 0; nd < 4; ++nd) {
                s16x8 vb = *(const s16x8*)&Vs[nd * 16 + l15][ks * 32 + lq * 8];
                acc_o[nd] = __builtin_amdgcn_mfma_f32_16x16x32_bf16(pa, vb, acc_o[nd], 0, 0, 0);
            }
        }
        __builtin_amdgcn_s_setprio(0);
    }

#pragma unroll
    for (int r = 0; r < 4; ++r) {
        float inv = 1.f / lsum[r];
        int rowg = q0 + wid * 16 + lq * 4 + r;
        u16* orow = o + ((size_t)b * SS + rowg) * CC + hh * DD;
#pragma unroll
        for (int nd = 0; nd < 4; ++nd)
            orow[nd * 16 + l15] = f2bf(acc_o[nd][r] * inv);
    }
}

// ---------------- loss (from lm_head partials) ----------------
__global__ __launch_bounds__(256) void lse_kernel(const float* __restrict__ partM,
                                                  const float* __restrict__ partS,
                                                  const float* __restrict__ logits,
                                                  const int* __restrict__ tgt,
                                                  float* __restrict__ lossp) {
    int row = blockIdx.x, tid = threadIdx.x;
    float m = -3.0e38f, s = 0.f;
    for (int i = tid; i < NBX; i += 256) {
        float pm = partM[(size_t)row * NBX + i];
        float ps = partS[(size_t)row * NBX + i];
        float nm = fmaxf(m, pm);
        s = s * __expf(m - nm) + ps * __expf(pm - nm);
        m = nm;
    }
#pragma unroll
    for (int off = 32; off; off >>= 1) {
        float om = __shfl_xor(m, off), os = __shfl_xor(s, off);
        float nm = fmaxf(m, om);
        s = s * __expf(m - nm) + os * __expf(om - nm);
        m = nm;
    }
    __shared__ float rm[4], rsh[4];
    int wid = tid >> 6;
    if ((tid & 63) == 0) { rm[wid] = m; rsh[wid] = s; }
    __syncthreads();
    if (tid == 0) {
        float M = fmaxf(fmaxf(rm[0], rm[1]), fmaxf(rm[2], rm[3]));
        float S = rsh[0] * __expf(rm[0] - M) + rsh[1] * __expf(rm[1] - M) +
                  rsh[2] * __expf(rm[2] - M) + rsh[3] * __expf(rm[3] - M);
        float lse = M + __logf(S);
        lossp[row] = lse - logits[(size_t)row * VV + tgt[row]];
    }
}

__global__ __launch_bounds__(256) void loss_reduce_kernel(const float* __restrict__ lossp,
                                                          float* __restrict__ out) {
    int tid = threadIdx.x;
    float s = 0.f;
    for (int i = tid; i < MM; i += 256) s += lossp[i];
#pragma unroll
    for (int off = 32; off; off >>= 1) s += __shfl_xor(s, off);
    __shared__ float r[4];
    if ((tid & 63) == 0) r[tid >> 6] = s;
    __syncthreads();
    if (tid == 0) out[0] = (r[0] + r[1] + r[2] + r[3]) * (1.0f / MM);
}

// ---------------- host ----------------
extern "C" void kernel_launch(void* const* d_in, const int* in_sizes, int n_in,
                              void* d_out, int out_size, void* d_ws, size_t ws_size,
                              hipStream_t stream) {
    const int*   idx     = (const int*)  d_in[0];
    const int*   targets = (const int*)  d_in[1];
    const float* wte     = (const float*)d_in[2];
    const float* wpe     = (const float*)d_in[3];
    const float* ln1w    = (const float*)d_in[4];
    const float* ln1b    = (const float*)d_in[5];
    const float* qkvw    = (const float*)d_in[6];
    const float* qkvbi   = (const float*)d_in[7];
    const float* projw   = (const float*)d_in[8];
    const float* projbi  = (const float*)d_in[9];
    const float* ln2w    = (const float*)d_in[10];
    const float* ln2b    = (const float*)d_in[11];
    const float* fcw     = (const float*)d_in[12];
    const float* fcbi    = (const float*)d_in[13];
    const float* fc2w    = (const float*)d_in[14];
    const float* fc2bi   = (const float*)d_in[15];
    const float* lnfw    = (const float*)d_in[16];
    const float* lnfb    = (const float*)d_in[17];
    float* logits = (float*)d_out;

    char* wsb = (char*)d_ws;
    size_t off = 0;
    auto alloc = [&](size_t n) -> char* {
        char* p = wsb + off;
        off = (off + n + 255) & ~(size_t)255;
        return p;
    };
    u16*   wteT  = (u16*)  alloc((size_t)VPAD * CC * 2);
    u16*   qkvT  = (u16*)  alloc((size_t)LNUM * 3 * CC * CC * 2);
    u16*   projT = (u16*)  alloc((size_t)LNUM * CC * CC * 2);
    u16*   fcT   = (u16*)  alloc((size_t)LNUM * FFD * CC * 2);
    u16*   fc2T  = (u16*)  alloc((size_t)LNUM * CC * FFD * 2);
    float* h     = (float*)alloc((size_t)MM * CC * 4);
    u16*   xb    = (u16*)  alloc((size_t)MM * CC * 2);
    u16*   qkvb  = (u16*)  alloc((size_t)MM * 3 * CC * 2);
    u16*   ob    = (u16*)  alloc((size_t)MM * CC * 2);
    u16*   gb    = (u16*)  alloc((size_t)MM * FFD * 2);
    u16*   vTb   = (u16*)  alloc((size_t)BB * HH * DD * SS * 2);
    float* lossp = (float*)alloc((size_t)MM * 4);
    float* partM = (float*)alloc((size_t)MM * NBX * 4);
    float* partS = (float*)alloc((size_t)MM * NBX * 4);

    // weight prep
    {
        int blocks = (int)(((size_t)VPAD * CC / 4 + 255) / 256);
        wte_conv_kernel<<<blocks, 256, 0, stream>>>(wte, wteT);
    }
    transpose_conv_kernel<<<dim3(3 * CC / 32, CC / 32, LNUM), dim3(32, 8), 0, stream>>>(qkvw, qkvT, CC, 3 * CC);
    transpose_conv_kernel<<<dim3(CC / 32, CC / 32, LNUM),     dim3(32, 8), 0, stream>>>(projw, projT, CC, CC);
    transpose_conv_kernel<<<dim3(FFD / 32, CC / 32, LNUM),    dim3(32, 8), 0, stream>>>(fcw, fcT, CC, FFD);
    transpose_conv_kernel<<<dim3(CC / 32, FFD / 32, LNUM),    dim3(32, 8), 0, stream>>>(fc2w, fc2T, FFD, CC);

    embed_kernel<<<MM, 256, 0, stream>>>(idx, wte, wpe, h);

    for (int l = 0; l < LNUM; ++l) {
        const u16* qkvT_l  = qkvT  + (size_t)l * 3 * CC * CC;
        const u16* projT_l = projT + (size_t)l * CC * CC;
        const u16* fcT_l   = fcT   + (size_t)l * FFD * CC;
        const u16* fc2T_l  = fc2T  + (size_t)l * CC * FFD;

        ln_kernel<<<MM, 256, 0, stream>>>(h, ln1w + (size_t)l * CC, ln1b + (size_t)l * CC, xb);
        gemm_bt_kernel<128, 128, 64, 0><<<dim3(3 * CC / 128, MM / 128), 256, 0, stream>>>(
            xb, qkvT_l, qkvbi + (size_t)l * 3 * CC, nullptr, qkvb, CC, 3 * CC, nullptr, nullptr);
        vtrans_kernel<<<dim3(SS / 64, BB * HH), 256, 0, stream>>>(qkvb, vTb);
        attn_mfma3_kernel<<<BB * HH * 16, 256, 0, stream>>>(qkvb, vTb, ob);
        gemm_bt_kernel<64, 64, 128, 2><<<dim3(CC / 64, MM / 64), 256, 0, stream>>>(
            ob, projT_l, projbi + (size_t)l * CC, h, nullptr, CC, CC, nullptr, nullptr);
        ln_kernel<<<MM, 256, 0, stream>>>(h, ln2w + (size_t)l * CC, ln2b + (size_t)l * CC, xb);
        gemm_bt_kernel<128, 128, 64, 1><<<dim3(FFD / 128, MM / 128), 256, 0, stream>>>(
            xb, fcT_l, fcbi + (size_t)l * FFD, nullptr, gb, CC, FFD, nullptr, nullptr);
        gemm_bt_kernel<64, 64, 128, 2><<<dim3(CC / 64, MM / 64), 256, 0, stream>>>(
            gb, fc2T_l, fc2bi + (size_t)l * CC, h, nullptr, FFD, CC, nullptr, nullptr);
    }

    ln_kernel<<<MM, 256, 0, stream>>>(h, lnfw, lnfb, xb);
    gemm_bt_kernel<128, 128, 64, 3><<<dim3(VPAD / 128, MM / 128), 256, 0, stream>>>(
        xb, wteT, nullptr, logits, nullptr, CC, VV, partM, partS);

    lse_kernel<<<MM, 256, 0, stream>>>(partM, partS, logits, targets, lossp);
    loss_reduce_kernel<<<1, 256, 0, stream>>>(lossp, logits + (size_t)MM * VV);
}

// Round 14
// 1907.936 us; speedup vs baseline: 1.0878x; 1.0129x over previous
//
#include <hip/hip_runtime.h>
#include <hip/hip_bf16.h>
#include <cstdint>
#include <cstddef>

// ---- model dims ----
constexpr int LNUM = 12;
constexpr int BB   = 2;
constexpr int SS   = 1024;
constexpr int CC   = 768;
constexpr int HH   = 12;
constexpr int DD   = 64;      // C/H
constexpr int FFD  = 3072;    // 4C
constexpr int VV   = 50257;
constexpr int VPAD = 50304;   // V rounded up to 128
constexpr int NBX  = VPAD / 128; // lm_head col-blocks = 393
constexpr int MM   = BB * SS; // 2048 token rows

typedef unsigned short u16;
typedef short     s16x8 __attribute__((ext_vector_type(8)));
typedef float     f32x4 __attribute__((ext_vector_type(4)));
typedef u16       u16x4 __attribute__((ext_vector_type(4)));
typedef u16       u16x8 __attribute__((ext_vector_type(8)));

__device__ __forceinline__ float bf2f(u16 v) {
    return __uint_as_float(((unsigned)v) << 16);
}
__device__ __forceinline__ u16 f2bf(float f) {
    unsigned u = __float_as_uint(f);
    return (u16)((u + 0x7fffu + ((u >> 16) & 1u)) >> 16);
}

// ---------------- weight prep ----------------

// wte [V][C] f32 -> bf16 [VPAD][C], pad rows zero
__global__ __launch_bounds__(256) void wte_conv_kernel(const float* __restrict__ wte,
                                                       u16* __restrict__ out) {
    size_t i4 = ((size_t)blockIdx.x * 256 + threadIdx.x) * 4;
    if (i4 >= (size_t)VPAD * CC) return;
    size_t r = i4 / CC;
    u16x4 o;
    if (r < (size_t)VV) {
        const float4 v = *(const float4*)&wte[i4];
        o[0] = f2bf(v.x); o[1] = f2bf(v.y); o[2] = f2bf(v.z); o[3] = f2bf(v.w);
    } else {
        o[0] = o[1] = o[2] = o[3] = 0;
    }
    *(u16x4*)&out[i4] = o;
}

// in: [L][R][Cn] f32   out: [L][Cn][R] bf16   (R,Cn multiples of 32)
__global__ __launch_bounds__(256) void transpose_conv_kernel(const float* __restrict__ in,
                                                             u16* __restrict__ out,
                                                             int R, int Cn) {
    __shared__ float tile[32][33];
    const float* inp = in + (size_t)blockIdx.z * R * Cn;
    u16* outp = out + (size_t)blockIdx.z * R * Cn;
    int c  = blockIdx.x * 32 + threadIdx.x;
    int r0 = blockIdx.y * 32;
#pragma unroll
    for (int i = 0; i < 4; ++i) {
        int r = r0 + threadIdx.y + i * 8;
        tile[threadIdx.y + i * 8][threadIdx.x] = inp[(size_t)r * Cn + c];
    }
    __syncthreads();
    int oc = r0 + threadIdx.x; // output col = input row (k)
#pragma unroll
    for (int i = 0; i < 4; ++i) {
        int orow = blockIdx.x * 32 + threadIdx.y + i * 8; // output row (n)
        outp[(size_t)orow * R + oc] = f2bf(tile[threadIdx.x][threadIdx.y + i * 8]);
    }
}

// ---------------- embedding ----------------
__global__ __launch_bounds__(256) void embed_kernel(const int* __restrict__ idx,
                                                    const float* __restrict__ wte,
                                                    const float* __restrict__ wpe,
                                                    float* __restrict__ h) {
    int row = blockIdx.x;          // 0..2047
    int s   = row & (SS - 1);
    int tok = idx[row];
    const float* we = wte + (size_t)tok * CC;
    const float* pe = wpe + (size_t)s * CC;
    float* hr = h + (size_t)row * CC;
    for (int c = threadIdx.x; c < CC; c += 256) hr[c] = we[c] + pe[c];
}

// ---------------- layernorm: f32 in -> bf16 out ----------------
__global__ __launch_bounds__(256) void ln_kernel(const float* __restrict__ h,
                                                 const float* __restrict__ w,
                                                 const float* __restrict__ b,
                                                 u16* __restrict__ x) {
    int row = blockIdx.x, tid = threadIdx.x;
    const float* hr = h + (size_t)row * CC;
    float v0 = hr[tid], v1 = hr[tid + 256], v2 = hr[tid + 512];
    float s  = v0 + v1 + v2;
    float s2 = v0 * v0 + v1 * v1 + v2 * v2;
#pragma unroll
    for (int off = 32; off; off >>= 1) {
        s  += __shfl_xor(s, off);
        s2 += __shfl_xor(s2, off);
    }
    __shared__ float rs[4], rs2[4], stat[2];
    int wid = tid >> 6;
    if ((tid & 63) == 0) { rs[wid] = s; rs2[wid] = s2; }
    __syncthreads();
    if (tid == 0) {
        float ts  = rs[0] + rs[1] + rs[2] + rs[3];
        float ts2 = rs2[0] + rs2[1] + rs2[2] + rs2[3];
        float mean = ts * (1.0f / CC);
        float var  = ts2 * (1.0f / CC) - mean * mean;
        stat[0] = mean;
        stat[1] = rsqrtf(var + 1e-5f);
    }
    __syncthreads();
    float mean = stat[0], rstd = stat[1];
    size_t base = (size_t)row * CC;
    x[base + tid]       = f2bf((v0 - mean) * rstd * w[tid]       + b[tid]);
    x[base + tid + 256] = f2bf((v1 - mean) * rstd * w[tid + 256] + b[tid + 256]);
    x[base + tid + 512] = f2bf((v2 - mean) * rstd * w[tid + 512] + b[tid + 512]);
}

// ---------------- GEMM: C[M,N] = A[M,K] @ Bt[N,K]^T  (bf16 in, f32 acc) ----------------
// Reg-staged (global->VGPR->LDS), single 32KB LDS buffer, 2-barrier loop,
// T14 async split; LDS XOR chunk-swizzle both-sides (XOR within each 8-chunk
// half: phys = ((p&7)^(r&7)) | (p&8), an involution); XCD-chunked remap.
// BK=64 for 128x128 tiles (LDS 32KB); BK=128 for 64x64 tiles (LDS still 32KB).
// EPI: 0 = bias -> bf16 out; V columns (col>=2C) routed TRANSPOSED to
//          vT[bh][d][s] via cached scattered u16x4 stores (L2 write-back
//          merges partial lines — r12's NT experiment proved bypass is what
//          doubles HBM writes). Replaces the standalone vtrans kernel.
//      1 = bias+gelu -> bf16 out   (fc; gelu via overflow-safe sigmoid form)
//      2 = bias, residual add into f32 outf (proj, fc2)
//      3 = no bias, f32 logits out (col<VV; regular cached store) + partials
template <int BM, int BN, int BK, int EPI>
__global__ __launch_bounds__(256)
void gemm_bt_kernel(const u16* __restrict__ A, const u16* __restrict__ Bt,
                    const float* __restrict__ bias, float* __restrict__ outf,
                    u16* __restrict__ outb, u16* __restrict__ vT,
                    int K, long long ldo,
                    float* __restrict__ partM, float* __restrict__ partS) {
    constexpr int MR  = BM / 32, NR = BN / 32;   // fragment repeats per wave
    constexpr int ACH = BM * BK / (256 * 8);     // staged A chunks per thread
    constexpr int BCH = BN * BK / (256 * 8);
    constexpr int CPR = BK / 8;                  // 16B chunks per LDS row
    __shared__ u16 As[BM * BK];
    __shared__ u16 Bs[BN * BK];
    const int tid  = threadIdx.x;
    const int lane = tid & 63;
    const int wid  = tid >> 6;
    const int l15  = lane & 15;
    const int lq   = lane >> 4;
    const int wm   = wid & 1;
    const int wn   = wid >> 1;
    const int rx   = l15 & 7;                    // read-side XOR chunk term

    // XCD-chunked bijective remap; work id is column-major (bx outer, by inner)
    const int gx = gridDim.x, gy = gridDim.y;
    const int nwg = gx * gy;
    const int pos = blockIdx.y * gx + blockIdx.x;      // dispatch order
    const int qc  = nwg >> 3, rc = nwg & 7;
    const int xcd = pos & 7, cidx = pos >> 3;
    const int wgid = (xcd < rc ? xcd * (qc + 1) : rc * (qc + 1) + (xcd - rc) * qc) + cidx;
    const int bx = wgid / gy, by = wgid % gy;
    const int bm0 = by * BM, bn0 = bx * BN;

    f32x4 acc[MR][NR];
#pragma unroll
    for (int m = 0; m < MR; ++m)
#pragma unroll
        for (int n = 0; n < NR; ++n) acc[m][n] = (f32x4){0.f, 0.f, 0.f, 0.f};

    u16x8 areg[ACH], breg[BCH];
    auto ldreg = [&](int kt) {
#pragma unroll
        for (int it = 0; it < ACH; ++it) {
            int g = it * 256 + tid, r = g / CPR, p = g % CPR;
            int c = ((((p & 7) ^ (r & 7)) | (p & 8))) * 8;
            areg[it] = *(const u16x8*)&A[(size_t)(bm0 + r) * (size_t)K + kt + c];
        }
#pragma unroll
        for (int it = 0; it < BCH; ++it) {
            int g = it * 256 + tid, r = g / CPR, p = g % CPR;
            int c = ((((p & 7) ^ (r & 7)) | (p & 8))) * 8;
            breg[it] = *(const u16x8*)&Bt[(size_t)(bn0 + r) * (size_t)K + kt + c];
        }
    };
    auto wlds = [&]() {
#pragma unroll
        for (int it = 0; it < ACH; ++it) *(u16x8*)&As[(it * 256 + tid) * 8] = areg[it];
#pragma unroll
        for (int it = 0; it < BCH; ++it) *(u16x8*)&Bs[(it * 256 + tid) * 8] = breg[it];
    };
    auto compute = [&]() {
#pragma unroll
        for (int ks = 0; ks < BK / 32; ++ks) {
            const int ck = ks * 4 + lq;
            const int co = (((ck & 7) ^ rx) | (ck & 8)) * 8;
            s16x8 af[MR], bfr[NR];
#pragma unroll
            for (int m = 0; m < MR; ++m) {
                int row = wm * (BM / 2) + m * 16 + l15;
                af[m] = *(const s16x8*)&As[row * BK + co];
            }
#pragma unroll
            for (int n = 0; n < NR; ++n) {
                int row = wn * (BN / 2) + n * 16 + l15;
                bfr[n] = *(const s16x8*)&Bs[row * BK + co];
            }
#pragma unroll
            for (int m = 0; m < MR; ++m)
#pragma unroll
                for (int n = 0; n < NR; ++n)
                    acc[m][n] = __builtin_amdgcn_mfma_f32_16x16x32_bf16(af[m], bfr[n], acc[m][n], 0, 0, 0);
        }
    };

    const int nk = K / BK;
    ldreg(0);
    for (int t = 0; t < nk; ++t) {
        __syncthreads();          // previous compute done; LDS free
        wlds();
        __syncthreads();          // tile visible to all waves
        if (t + 1 < nk) ldreg((t + 1) * BK);  // issue next loads under compute
        compute();
    }

    // epilogue: C/D layout col=lane&15, row=4*(lane>>4)+reg
#pragma unroll
    for (int m = 0; m < MR; ++m) {
#pragma unroll
        for (int n = 0; n < NR; ++n) {
            int col = bn0 + wn * (BN / 2) + n * 16 + l15;
            if (EPI == 0 && col >= 2 * CC) {
                // V columns: write transposed to vT[bh][d][s]; 4 consecutive s
                // per lane. Scattered 8B cached stores merge in write-back L2.
                int hd  = col - 2 * CC;
                int hh2 = hd >> 6, d = hd & 63;
                int rowg0 = bm0 + wm * (BM / 2) + m * 16 + lq * 4;
                int b2 = rowg0 >> 10, s0 = rowg0 & (SS - 1);
                u16x4 o4;
#pragma unroll
                for (int r = 0; r < 4; ++r) o4[r] = f2bf(acc[m][n][r] + bias[col]);
                *(u16x4*)&vT[(((size_t)(b2 * HH + hh2)) * DD + d) * SS + s0] = o4;
                continue;
            }
#pragma unroll
            for (int r = 0; r < 4; ++r) {
                int row = bm0 + wm * (BM / 2) + m * 16 + lq * 4 + r;
                float v = acc[m][n][r];
                if (EPI != 3) v += bias[col];
                if (EPI == 1) {
                    // gelu(tanh approx) == v * sigmoid(2*z); overflow-safe
                    float z = 0.7978845608028654f * (v + 0.044715f * v * v * v);
                    v = v / (1.0f + __expf(-2.0f * z));
                }
                if (EPI == 0 || EPI == 1) {
                    outb[(size_t)row * ldo + col] = f2bf(v);
                } else if (EPI == 2) {
                    outf[(size_t)row * ldo + col] += v;
                } else {
                    if (col < VV) outf[(size_t)row * ldo + col] = v;
                }
            }
        }
    }

    // lm_head: per-row partial logsumexp over this block's BN cols
    if constexpr (EPI == 3) {
        __shared__ float redM[2][BM], redS[2][BM];
#pragma unroll
        for (int m = 0; m < MR; ++m) {
#pragma unroll
            for (int r = 0; r < 4; ++r) {
                float mx = -3.0e38f;
#pragma unroll
                for (int n = 0; n < NR; ++n) {
                    int colg = bn0 + wn * (BN / 2) + n * 16 + l15;
                    float v = (colg < VV) ? acc[m][n][r] : -3.0e38f;
                    mx = fmaxf(mx, v);
                }
#pragma unroll
                for (int off = 1; off < 16; off <<= 1) mx = fmaxf(mx, __shfl_xor(mx, off));
                float sm = 0.f;
#pragma unroll
                for (int n = 0; n < NR; ++n) {
                    int colg = bn0 + wn * (BN / 2) + n * 16 + l15;
                    if (colg < VV) sm += __expf(acc[m][n][r] - mx);
                }
#pragma unroll
                for (int off = 1; off < 16; off <<= 1) sm += __shfl_xor(sm, off);
                if (l15 == 0) {
                    int rl = wm * (BM / 2) + m * 16 + lq * 4 + r;
                    redM[wn][rl] = mx;
                    redS[wn][rl] = sm;
                }
            }
        }
        __syncthreads();
        if (tid < BM) {
            float m0 = redM[0][tid], m1 = redM[1][tid];
            float M = fmaxf(m0, m1);
            float S = redS[0][tid] * __expf(m0 - M) + redS[1][tid] * __expf(m1 - M);
            size_t rowg = (size_t)(bm0 + tid);
            partM[rowg * NBX + bx] = M;
            partS[rowg * NBX + bx] = S;
        }
    }
}

// ---------------- MFMA flash attention v3.2 (T14 prefetch + T5 setprio) ----------------
// Block = one 64-row q-tile j of one (b,h); keys 0..j. 4 waves x 16 rows.
// grid = B*H*16 = 384; pos = (15-j)*24 + bh  ->  heavy tiles dispatch first,
// all 16 j-blocks of a bh share one XCD (24 % 8 == 0) for K/V L2 reuse.
__global__ __launch_bounds__(256) void attn_mfma3_kernel(const u16* __restrict__ qkv,
                                                         const u16* __restrict__ vT,
                                                         u16* __restrict__ o) {
    constexpr int PADC = 72;
    __shared__ u16 Ks[64][PADC];     // K[t][d]
    __shared__ u16 Vs[64][PADC];     // V^T[d][t]
    __shared__ u16 Ps[4][16][PADC];  // per-wave P tile [row][t]

    const int tid = threadIdx.x, lane = tid & 63, wid = tid >> 6;
    const int l15 = lane & 15, lq = lane >> 4;
    const int pos = blockIdx.x;                 // 0..383
    const int j   = 15 - pos / 24;              // q-tile index, heavy first
    const int bh  = pos % 24;
    const int b   = bh / HH, hh = bh % HH;
    const int q0  = j * 64;

    const size_t base = (size_t)b * SS * (3 * CC);
    const u16* kp = qkv + base + CC + hh * DD;
    const u16* vp = vT + (size_t)bh * DD * SS;

    s16x8 qf[2];
    {
        const u16* qr = qkv + base + hh * DD + (size_t)(q0 + wid * 16 + l15) * (3 * CC);
        qf[0] = *(const s16x8*)&qr[lq * 8];
        qf[1] = *(const s16x8*)&qr[32 + lq * 8];
    }

    float m[4], lsum[4];
    f32x4 acc_o[4];
#pragma unroll
    for (int r = 0; r < 4; ++r) { m[r] = -3.0e38f; lsum[r] = 0.f; }
#pragma unroll
    for (int nd = 0; nd < 4; ++nd) acc_o[nd] = (f32x4){0.f, 0.f, 0.f, 0.f};

    // per-thread staged K/V chunks (T14: load t+1 during compute of t)
    const int sr = tid >> 3, sc = (tid & 7) * 8;   // staging row / col for it=0
    const int sr1 = sr + 32;                        // it=1 covers rows 32..63
    u16x8 kreg[2], vreg[2];
    auto ldkv = [&](int t0) {
        kreg[0] = *(const u16x8*)&kp[(size_t)(t0 + sr) * (3 * CC) + sc];
        vreg[0] = *(const u16x8*)&vp[(size_t)sr * SS + t0 + sc];
        kreg[1] = *(const u16x8*)&kp[(size_t)(t0 + sr1) * (3 * CC) + sc];
        vreg[1] = *(const u16x8*)&vp[(size_t)sr1 * SS + t0 + sc];
    };

    ldkv(0);
    for (int tt = 0; tt <= j; ++tt) {
        __syncthreads();   // all waves done reading previous K/V tiles
        *(u16x8*)&Ks[sr][sc]  = kreg[0];
        *(u16x8*)&Vs[sr][sc]  = vreg[0];
        *(u16x8*)&Ks[sr1][sc] = kreg[1];
        *(u16x8*)&Vs[sr1][sc] = vreg[1];
        __syncthreads();
        if (tt < j) ldkv((tt + 1) * 64);  // issue next tile's loads under compute

        // QK^T (T5: boost wave priority through the MFMA cluster)
        f32x4 sc4[4];
#pragma unroll
        for (int n = 0; n < 4; ++n) sc4[n] = (f32x4){0.f, 0.f, 0.f, 0.f};
        __builtin_amdgcn_s_setprio(1);
#pragma unroll
        for (int ks = 0; ks < 2; ++ks) {
#pragma unroll
            for (int n = 0; n < 4; ++n) {
                s16x8 kb = *(const s16x8*)&Ks[n * 16 + l15][ks * 32 + lq * 8];
                sc4[n] = __builtin_amdgcn_mfma_f32_16x16x32_bf16(qf[ks], kb, sc4[n], 0, 0, 0);
            }
        }
        __builtin_amdgcn_s_setprio(0);

        const int t0 = tt * 64;
        if (tt == j) {
#pragma unroll
            for (int n = 0; n < 4; ++n) {
                int colg = t0 + n * 16 + l15;
#pragma unroll
                for (int r = 0; r < 4; ++r) {
                    int rowg = q0 + wid * 16 + lq * 4 + r;
                    float sv = sc4[n][r] * 0.125f;
                    sc4[n][r] = (colg <= rowg) ? sv : -3.0e38f;
                }
            }
        } else {
#pragma unroll
            for (int n = 0; n < 4; ++n)
#pragma unroll
                for (int r = 0; r < 4; ++r) sc4[n][r] *= 0.125f;
        }

        // online softmax
        float mt[4];
#pragma unroll
        for (int r = 0; r < 4; ++r)
            mt[r] = fmaxf(fmaxf(sc4[0][r], sc4[1][r]), fmaxf(sc4[2][r], sc4[3][r]));
#pragma unroll
        for (int off = 1; off < 16; off <<= 1)
#pragma unroll
            for (int r = 0; r < 4; ++r) mt[r] = fmaxf(mt[r], __shfl_xor(mt[r], off));
        float rs[4];
#pragma unroll
        for (int r = 0; r < 4; ++r) {
            float mn  = fmaxf(m[r], mt[r]);
            float scl = __expf(m[r] - mn);
            m[r] = mn;
            float ps = 0.f;
#pragma unroll
            for (int n = 0; n < 4; ++n) {
                float p = __expf(sc4[n][r] - mn);
                sc4[n][r] = p;
                ps += p;
            }
            rs[r] = ps;
            lsum[r] *= scl;
#pragma unroll
            for (int nd = 0; nd < 4; ++nd) acc_o[nd][r] *= scl;
        }
#pragma unroll
        for (int off = 1; off < 16; off <<= 1)
#pragma unroll
            for (int r = 0; r < 4; ++r) rs[r] += __shfl_xor(rs[r], off);
#pragma unroll
        for (int r = 0; r < 4; ++r) lsum[r] += rs[r];

        // P -> LDS (wave-private; no barrier needed before PV reads)
#pragma unroll
        for (int n = 0; n < 4; ++n)
#pragma unroll
            for (int r = 0; r < 4; ++r)
                Ps[wid][lq * 4 + r][n * 16 + l15] = f2bf(sc4[n][r]);

        // PV (T5)
        __builtin_amdgcn_s_setprio(1);
#pragma unroll
        for (int ks = 0; ks < 2; ++ks) {
            s16x8 pa = *(const s16x8*)&Ps[wid][l15][ks * 32 + lq * 8];
#pragma unroll
            for (int nd = 0; nd < 4; ++nd) {
                s16x8 vb = *(const s16x8*)&Vs[nd * 16 + l15][ks * 32 + lq * 8];
                acc_o[nd] = __builtin_amdgcn_mfma_f32_16x16x32_bf16(pa, vb, acc_o[nd], 0, 0, 0);
            }
        }
        __builtin_amdgcn_s_setprio(0);
    }

#pragma unroll
    for (int r = 0; r < 4; ++r) {
        float inv = 1.f / lsum[r];
        int rowg = q0 + wid * 16 + lq * 4 + r;
        u16* orow = o + ((size_t)b * SS + rowg) * CC + hh * DD;
#pragma unroll
        for (int nd = 0; nd < 4; ++nd)
            orow[nd * 16 + l15] = f2bf(acc_o[nd][r] * inv);
    }
}

// ---------------- loss (from lm_head partials) ----------------
__global__ __launch_bounds__(256) void lse_kernel(const float* __restrict__ partM,
                                                  const float* __restrict__ partS,
                                                  const float* __restrict__ logits,
                                                  const int* __restrict__ tgt,
                                                  float* __restrict__ lossp) {
    int row = blockIdx.x, tid = threadIdx.x;
    float m = -3.0e38f, s = 0.f;
    for (int i = tid; i < NBX; i += 256) {
        float pm = partM[(size_t)row * NBX + i];
        float ps = partS[(size_t)row * NBX + i];
        float nm = fmaxf(m, pm);
        s = s * __expf(m - nm) + ps * __expf(pm - nm);
        m = nm;
    }
#pragma unroll
    for (int off = 32; off; off >>= 1) {
        float om = __shfl_xor(m, off), os = __shfl_xor(s, off);
        float nm = fmaxf(m, om);
        s = s * __expf(m - nm) + os * __expf(om - nm);
        m = nm;
    }
    __shared__ float rm[4], rsh[4];
    int wid = tid >> 6;
    if ((tid & 63) == 0) { rm[wid] = m; rsh[wid] = s; }
    __syncthreads();
    if (tid == 0) {
        float M = fmaxf(fmaxf(rm[0], rm[1]), fmaxf(rm[2], rm[3]));
        float S = rsh[0] * __expf(rm[0] - M) + rsh[1] * __expf(rm[1] - M) +
                  rsh[2] * __expf(rm[2] - M) + rsh[3] * __expf(rm[3] - M);
        float lse = M + __logf(S);
        lossp[row] = lse - logits[(size_t)row * VV + tgt[row]];
    }
}

__global__ __launch_bounds__(256) void loss_reduce_kernel(const float* __restrict__ lossp,
                                                          float* __restrict__ out) {
    int tid = threadIdx.x;
    float s = 0.f;
    for (int i = tid; i < MM; i += 256) s += lossp[i];
#pragma unroll
    for (int off = 32; off; off >>= 1) s += __shfl_xor(s, off);
    __shared__ float r[4];
    if ((tid & 63) == 0) r[tid >> 6] = s;
    __syncthreads();
    if (tid == 0) out[0] = (r[0] + r[1] + r[2] + r[3]) * (1.0f / MM);
}

// ---------------- host ----------------
extern "C" void kernel_launch(void* const* d_in, const int* in_sizes, int n_in,
                              void* d_out, int out_size, void* d_ws, size_t ws_size,
                              hipStream_t stream) {
    const int*   idx     = (const int*)  d_in[0];
    const int*   targets = (const int*)  d_in[1];
    const float* wte     = (const float*)d_in[2];
    const float* wpe     = (const float*)d_in[3];
    const float* ln1w    = (const float*)d_in[4];
    const float* ln1b    = (const float*)d_in[5];
    const float* qkvw    = (const float*)d_in[6];
    const float* qkvbi   = (const float*)d_in[7];
    const float* projw   = (const float*)d_in[8];
    const float* projbi  = (const float*)d_in[9];
    const float* ln2w    = (const float*)d_in[10];
    const float* ln2b    = (const float*)d_in[11];
    const float* fcw     = (const float*)d_in[12];
    const float* fcbi    = (const float*)d_in[13];
    const float* fc2w    = (const float*)d_in[14];
    const float* fc2bi   = (const float*)d_in[15];
    const float* lnfw    = (const float*)d_in[16];
    const float* lnfb    = (const float*)d_in[17];
    float* logits = (float*)d_out;

    char* wsb = (char*)d_ws;
    size_t off = 0;
    auto alloc = [&](size_t n) -> char* {
        char* p = wsb + off;
        off = (off + n + 255) & ~(size_t)255;
        return p;
    };
    u16*   wteT  = (u16*)  alloc((size_t)VPAD * CC * 2);
    u16*   qkvT  = (u16*)  alloc((size_t)LNUM * 3 * CC * CC * 2);
    u16*   projT = (u16*)  alloc((size_t)LNUM * CC * CC * 2);
    u16*   fcT   = (u16*)  alloc((size_t)LNUM * FFD * CC * 2);
    u16*   fc2T  = (u16*)  alloc((size_t)LNUM * CC * FFD * 2);
    float* h     = (float*)alloc((size_t)MM * CC * 4);
    u16*   xb    = (u16*)  alloc((size_t)MM * CC * 2);
    u16*   qkvb  = (u16*)  alloc((size_t)MM * 3 * CC * 2);
    u16*   ob    = (u16*)  alloc((size_t)MM * CC * 2);
    u16*   gb    = (u16*)  alloc((size_t)MM * FFD * 2);
    u16*   vTb   = (u16*)  alloc((size_t)BB * HH * DD * SS * 2);
    float* lossp = (float*)alloc((size_t)MM * 4);
    float* partM = (float*)alloc((size_t)MM * NBX * 4);
    float* partS = (float*)alloc((size_t)MM * NBX * 4);

    // weight prep
    {
        int blocks = (int)(((size_t)VPAD * CC / 4 + 255) / 256);
        wte_conv_kernel<<<blocks, 256, 0, stream>>>(wte, wteT);
    }
    transpose_conv_kernel<<<dim3(3 * CC / 32, CC / 32, LNUM), dim3(32, 8), 0, stream>>>(qkvw, qkvT, CC, 3 * CC);
    transpose_conv_kernel<<<dim3(CC / 32, CC / 32, LNUM),     dim3(32, 8), 0, stream>>>(projw, projT, CC, CC);
    transpose_conv_kernel<<<dim3(FFD / 32, CC / 32, LNUM),    dim3(32, 8), 0, stream>>>(fcw, fcT, CC, FFD);
    transpose_conv_kernel<<<dim3(CC / 32, FFD / 32, LNUM),    dim3(32, 8), 0, stream>>>(fc2w, fc2T, FFD, CC);

    embed_kernel<<<MM, 256, 0, stream>>>(idx, wte, wpe, h);

    for (int l = 0; l < LNUM; ++l) {
        const u16* qkvT_l  = qkvT  + (size_t)l * 3 * CC * CC;
        const u16* projT_l = projT + (size_t)l * CC * CC;
        const u16* fcT_l   = fcT   + (size_t)l * FFD * CC;
        const u16* fc2T_l  = fc2T  + (size_t)l * CC * FFD;

        ln_kernel<<<MM, 256, 0, stream>>>(h, ln1w + (size_t)l * CC, ln1b + (size_t)l * CC, xb);
        // qkv: Q,K -> qkvb; V routed transposed to vTb in the epilogue
        gemm_bt_kernel<128, 128, 64, 0><<<dim3(3 * CC / 128, MM / 128), 256, 0, stream>>>(
            xb, qkvT_l, qkvbi + (size_t)l * 3 * CC, nullptr, qkvb, vTb, CC, 3 * CC, nullptr, nullptr);
        attn_mfma3_kernel<<<BB * HH * 16, 256, 0, stream>>>(qkvb, vTb, ob);
        gemm_bt_kernel<64, 64, 128, 2><<<dim3(CC / 64, MM / 64), 256, 0, stream>>>(
            ob, projT_l, projbi + (size_t)l * CC, h, nullptr, nullptr, CC, CC, nullptr, nullptr);
        ln_kernel<<<MM, 256, 0, stream>>>(h, ln2w + (size_t)l * CC, ln2b + (size_t)l * CC, xb);
        gemm_bt_kernel<128, 128, 64, 1><<<dim3(FFD / 128, MM / 128), 256, 0, stream>>>(
            xb, fcT_l, fcbi + (size_t)l * FFD, nullptr, gb, nullptr, CC, FFD, nullptr, nullptr);
        gemm_bt_kernel<64, 64, 128, 2><<<dim3(CC / 64, MM / 64), 256, 0, stream>>>(
            gb, fc2T_l, fc2bi + (size_t)l * CC, h, nullptr, nullptr, FFD, CC, nullptr, nullptr);
    }

    ln_kernel<<<MM, 256, 0, stream>>>(h, lnfw, lnfb, xb);
    gemm_bt_kernel<128, 128, 64, 3><<<dim3(VPAD / 128, MM / 128), 256, 0, stream>>>(
        xb, wteT, nullptr, logits, nullptr, nullptr, CC, VV, partM, partS);

    lse_kernel<<<MM, 256, 0, stream>>>(partM, partS, logits, targets, lossp);
    loss_reduce_kernel<<<1, 256, 0, stream>>>(lossp, logits + (size_t)MM * VV);
}